// Round 2
// baseline (231.390 us; speedup 1.0000x reference)
//
#include <hip/hip_runtime.h>

// LinearConv2D: y[b, o=g*8+n, fi, t] =
//   sum_{d<8, fr<2, w<16} x[b, g*8+d, 2*fi+fr, 4*t+w] * wt[g*8+n, d, 2*fi+fr, w]
// Shapes: x[16,64,128,256] f32, wt[64,8,128,16] f32, out[16,64,64,61] f32.
//
// R9: the R4-R8 plateau decoded. rocprof top-5 shows only fillBufferAligned
// (~78.5us x2 = 157us of harness re-poison INSIDE the timed graph); our
// kernel never appears => its device time is <78us (~47us inferred). dur_us
// floor ~= 157 + 24 (kernel HBM floor) = ~181. The kernel itself is
// latency-bound at 2 waves/SIMD (VGPR ~220, grid 512 = 2 blocks/CU): all
// component floors (VALU 13.6, HBM 21, LDS port 20, L1 ~14us) are ~half of
// the ~47us => nothing hides the ds/load waits.
// Fix: lane = (t_local 32) x (w_half 2). Each lane does half the w-window,
// one __shfl_xor(32) combine at the end.
//  - x regs halve (2+2 float4/b) -> ~140 VGPR -> __launch_bounds__(256,3).
//  - grid x2 via t-split (z in {0,1}) -> 1024 blocks -> 12 waves/CU.
//  - L1 traffic halves (lane overlap 4.3x -> 2.2x); HBM stays 1x (t-halves
//    overlap 48B/row); LDS total unchanged, reads 2-way broadcast (free).
//  - Spill tripwire: WRITE_SIZE must stay ~17MB.

namespace {
constexpr int kB  = 16;
constexpr int kC  = 64;
constexpr int kF  = 128;
constexpr int kT  = 256;
constexpr int kG  = 8;
constexpr int kD  = 8;
constexpr int kN  = 8;
constexpr int kW  = 16;
constexpr int kKS = 4;
constexpr int kNT = 61;   // (256-16)/4 + 1
constexpr int kO  = 64;
constexpr int kFP = 64;   // (128-2)/2 + 1
constexpr int kWStride = kD * kF * kW;  // 16384: per-n weight stride (floats)
}

__global__ __launch_bounds__(256, 3)
void lc2d_kernel(const float* __restrict__ x,
                 const float* __restrict__ wt,
                 float* __restrict__ out) {
  // Weight slice for this (g,fi): 8n x 8d x 2fr x 16w = 2048 f32 = 8 KB.
  __shared__ float4 wlds[512];

  const int tid  = threadIdx.x;
  const int lane = tid & 63;
  const int wq   = tid >> 6;     // b-quad id (4 waves x 4 b = 16 b)
  const int tl   = lane & 31;    // t within this block's t-half
  const int th   = lane >> 5;    // w-half: lane handles w in [th*8, th*8+8)
  const int fi   = blockIdx.x;   // 0..63
  const int g    = blockIdx.y;   // 0..7
  const int tz   = blockIdx.z;   // 0..1  t-half

  // ---- Stage weights -> LDS (one-time, coalesced in 128B runs of 8 thr) ----
  // Layout: quad q = n*64 + (d*2+fr)*4 + qq, qq = w-quad 0..3.
  {
    const float* wb = wt + ((size_t)(g * kN) * kD * kF + (size_t)fi * 2) * kW;
#pragma unroll
    for (int r = 0; r < 2; ++r) {
      const int q  = tid + r * 256;      // 0..511
      const int n  = q >> 6;
      const int dd = (q >> 3) & 7;
      const int fr = (q >> 2) & 1;
      const int qq = q & 3;
      const float* src =
          wb + (size_t)n * kWStride + dd * (kF * kW) + fr * kW + qq * 4;
      wlds[q] = *(const float4*)src;
    }
  }

  // Global t for this lane; clamp inactive lanes (tz=1, tl>28) in-bounds.
  const int tg = tz * 32 + tl;                       // 0..63
  const int tc = (tg < kNT) ? tl : (kNT - 1 - 32);   // tz=1 clamp -> 28
  const int tau0 = (tz * 32 + tc) * kKS + th * 8;    // max 240+8=248; +8 = 256 OK

  const float* xb[4];
#pragma unroll
  for (int bb = 0; bb < 4; ++bb) {
    const int b = wq * 4 + bb;
    xb[bb] = x + (((size_t)b * kC + g * kD) * kF + fi * 2) * kT + tau0;
  }

  float acc[4][kN];
#pragma unroll
  for (int bb = 0; bb < 4; ++bb)
#pragma unroll
    for (int n = 0; n < kN; ++n) acc[bb][n] = 0.f;

  // Prime x register double-buffer with row 0 (d=0, fr=0): 2 float4 per b
  // (this lane's w-half only).
  float4 cur[4][2];
#pragma unroll
  for (int bb = 0; bb < 4; ++bb)
#pragma unroll
    for (int q = 0; q < 2; ++q) cur[bb][q] = ((const float4*)xb[bb])[q];

  __syncthreads();   // weights visible before first wlds read

#pragma unroll 2
  for (int it = 0; it < 16; ++it) {
    // Prefetch next x row for all 4 b (it==15 reloads row 15 — L1 hit).
    const int nx = (it < 15) ? it + 1 : 15;
    const size_t roff = ((size_t)(nx >> 1) * kF + (nx & 1)) * kT;
    float4 pre[4][2];
#pragma unroll
    for (int bb = 0; bb < 4; ++bb) {
      const float* xr = xb[bb] + roff;
#pragma unroll
      for (int q = 0; q < 2; ++q) pre[bb][q] = ((const float4*)xr)[q];
    }

    // Weight quads for (d=it>>1, fr=it&1), this lane's w-half:
    // quads it*4 + th*2 + {0,1}, per-n stride 64 quads. Two distinct
    // addresses per ds_read (th groups) -> 2-way broadcast, conflict-free.
    const float4* wrow = &wlds[it * 4 + th * 2];
#pragma unroll
    for (int n = 0; n < kN; ++n) {
      const float4 w0 = wrow[n * 64];
      const float4 w1 = wrow[n * 64 + 1];
#pragma unroll
      for (int bb = 0; bb < 4; ++bb) {
        float a = acc[bb][n];
        a = fmaf(cur[bb][0].x, w0.x, a);
        a = fmaf(cur[bb][0].y, w0.y, a);
        a = fmaf(cur[bb][0].z, w0.z, a);
        a = fmaf(cur[bb][0].w, w0.w, a);
        a = fmaf(cur[bb][1].x, w1.x, a);
        a = fmaf(cur[bb][1].y, w1.y, a);
        a = fmaf(cur[bb][1].z, w1.z, a);
        a = fmaf(cur[bb][1].w, w1.w, a);
        acc[bb][n] = a;
      }
    }

#pragma unroll
    for (int bb = 0; bb < 4; ++bb)
#pragma unroll
      for (int q = 0; q < 2; ++q) cur[bb][q] = pre[bb][q];
  }

  // Combine the two w-halves: lane (tl, th) <-> (tl, th^1).
#pragma unroll
  for (int bb = 0; bb < 4; ++bb)
#pragma unroll
    for (int n = 0; n < kN; ++n)
      acc[bb][n] += __shfl_xor(acc[bb][n], 32);

  // Store: th=0 lanes write n 0..3, th=1 lanes write n 4..7 (both halves
  // hold the full sum). For fixed (b,n), 32 lanes store 32 consecutive t.
  if (tg < kNT) {
    const size_t s = (size_t)kFP * kNT;
    const int nb = th * 4;
#pragma unroll
    for (int bb = 0; bb < 4; ++bb) {
      const int b = wq * 4 + bb;
      float* ob =
          out + (((size_t)b * kO + g * kN + nb) * kFP + fi) * (size_t)kNT + tg;
#pragma unroll
      for (int j = 0; j < 4; ++j) ob[(size_t)j * s] = acc[bb][nb + j];
    }
  }
}

extern "C" void kernel_launch(void* const* d_in, const int* in_sizes, int n_in,
                              void* d_out, int out_size, void* d_ws, size_t ws_size,
                              hipStream_t stream) {
  const float* x  = (const float*)d_in[0];
  const float* wt = (const float*)d_in[1];
  float* out      = (float*)d_out;

  dim3 grid(kFP, kG, 2);   // 64 x 8 x 2 = 1024 blocks of 256 threads
  lc2d_kernel<<<grid, 256, 0, stream>>>(x, wt, out);
}

// Round 3
// 217.831 us; speedup vs baseline: 1.0622x; 1.0622x over previous
//
#include <hip/hip_runtime.h>

// LinearConv2D: y[b, o=g*8+n, fi, t] =
//   sum_{d<8, fr<2, w<16} x[b, g*8+d, 2*fi+fr, 4*t+w] * wt[g*8+n, d, 2*fi+fr, w]
// Shapes: x[16,64,128,256] f32, wt[64,8,128,16] f32, out[16,64,64,61] f32.
//
// R10: R9 post-mortem. Kernel row finally visible: 92.9us, VGPR=72 (< the 96
// my buffers need) => compiler COLLAPSED the x double-buffer (sank prefetch
// loads to use => vmcnt stall per it), and R9 had dropped R8's n-ahead weight
// pipeline (per n: ds_read -> wait ~120cy -> 64cy FMA). ~46k stall cy/wave
// explains 92.9us. Harness re-poison fills = ~157us of dur_us; kernel is the
// remaining lever. R9's occupancy shape was right (4 waves/SIMD of work vs
// R8's 2); its scheduling was wrong.
// Fix, keeping R9's decomposition:
//  - manual unroll-2 it-loop, two NAMED x buffers (no pre->cur copies to
//    collapse); loads issue a full it (~700cy) before use -> counted vmcnt.
//  - 2-deep weight pipeline: n+2's ds_read_b128 pair issued before n's FMA
//    block -> 128cy issue-to-use >= ~120cy ds latency; only n=0 fills.
//  - __launch_bounds__(256,4): target 128 VGPR (demand ~128), keeps buffers.
//    Spill tripwire: WRITE_SIZE must stay ~19.6MB.
// Predicted: kernel ~30-40us, dur ~180-195, VALUBusy 45-60%.

namespace {
constexpr int kB  = 16;
constexpr int kC  = 64;
constexpr int kF  = 128;
constexpr int kT  = 256;
constexpr int kG  = 8;
constexpr int kD  = 8;
constexpr int kN  = 8;
constexpr int kW  = 16;
constexpr int kKS = 4;
constexpr int kNT = 61;   // (256-16)/4 + 1
constexpr int kO  = 64;
constexpr int kFP = 64;   // (128-2)/2 + 1
constexpr int kWStride = kD * kF * kW;  // 16384: per-n weight stride (floats)
}

__global__ __launch_bounds__(256, 4)
void lc2d_kernel(const float* __restrict__ x,
                 const float* __restrict__ wt,
                 float* __restrict__ out) {
  // Weight slice for this (g,fi): 8n x 8d x 2fr x 16w = 2048 f32 = 8 KB.
  __shared__ float4 wlds[512];

  const int tid  = threadIdx.x;
  const int lane = tid & 63;
  const int wq   = tid >> 6;     // b-quad id (4 waves x 4 b = 16 b)
  const int tl   = lane & 31;    // t within this block's t-half
  const int th   = lane >> 5;    // w-half: lane handles w in [th*8, th*8+8)
  const int fi   = blockIdx.x;   // 0..63
  const int g    = blockIdx.y;   // 0..7
  const int tz   = blockIdx.z;   // 0..1  t-half

  // ---- Stage weights -> LDS (one-time, coalesced in 128B runs of 8 thr) ----
  // Layout: quad q = n*64 + (d*2+fr)*4 + qq, qq = w-quad 0..3.
  {
    const float* wb = wt + ((size_t)(g * kN) * kD * kF + (size_t)fi * 2) * kW;
#pragma unroll
    for (int r = 0; r < 2; ++r) {
      const int q  = tid + r * 256;      // 0..511
      const int n  = q >> 6;
      const int dd = (q >> 3) & 7;
      const int fr = (q >> 2) & 1;
      const int qq = q & 3;
      const float* src =
          wb + (size_t)n * kWStride + dd * (kF * kW) + fr * kW + qq * 4;
      wlds[q] = *(const float4*)src;
    }
  }

  // Global t for this lane; clamp inactive lanes (tz=1, tl>28) in-bounds.
  const int tg = tz * 32 + tl;                       // 0..63
  const int tc = (tg < kNT) ? tl : (kNT - 1 - 32);   // tz=1 clamp -> 28
  const int tau0 = (tz * 32 + tc) * kKS + th * 8;    // max 248; +8 = 256 OK

  const float* xb[4];
#pragma unroll
  for (int bb = 0; bb < 4; ++bb) {
    const int b = wq * 4 + bb;
    xb[bb] = x + (((size_t)b * kC + g * kD) * kF + fi * 2) * kT + tau0;
  }

  float acc[4][kN];
#pragma unroll
  for (int bb = 0; bb < 4; ++bb)
#pragma unroll
    for (int n = 0; n < kN; ++n) acc[bb][n] = 0.f;

  // Prime buffer A with row 0 (d=0, fr=0): 2 float4 per b (this w-half).
  float4 bufA[4][2], bufB[4][2];
#pragma unroll
  for (int bb = 0; bb < 4; ++bb) {
    bufA[bb][0] = ((const float4*)xb[bb])[0];
    bufA[bb][1] = ((const float4*)xb[bb])[1];
  }

  __syncthreads();   // weights visible before first wlds read

  // One it: prefetch x row for it+1 into NXT, 2-deep-pipelined weight reads,
  // 8n x 4b x 8w FMAs out of CUR. All n/bb indexing compile-time.
#define IT_BODY(IT, CUR, NXT)                                              \
  {                                                                        \
    const int nx_ = ((IT) < 15) ? (IT) + 1 : 15;                           \
    const size_t roff_ = ((size_t)(nx_ >> 1) * kF + (nx_ & 1)) * kT;       \
    _Pragma("unroll")                                                      \
    for (int bb = 0; bb < 4; ++bb) {                                       \
      const float* xr_ = xb[bb] + roff_;                                   \
      NXT[bb][0] = ((const float4*)xr_)[0];                                \
      NXT[bb][1] = ((const float4*)xr_)[1];                                \
    }                                                                      \
    const float4* wrow_ = &wlds[(IT) * 4 + th * 2];                        \
    float4 wE0 = wrow_[0],  wE1 = wrow_[1];   /* n=0 */                    \
    float4 wO0 = wrow_[64], wO1 = wrow_[65];  /* n=1 */                    \
    _Pragma("unroll")                                                      \
    for (int n = 0; n < kN; ++n) {                                         \
      const float4 w0 = (n & 1) ? wO0 : wE0;                               \
      const float4 w1 = (n & 1) ? wO1 : wE1;                               \
      if (n + 2 < kN) {  /* refill this parity slot with n+2's quads */    \
        const float4* wr2_ = &wrow_[(n + 2) * 64];                         \
        if (n & 1) { wO0 = wr2_[0]; wO1 = wr2_[1]; }                       \
        else       { wE0 = wr2_[0]; wE1 = wr2_[1]; }                       \
      }                                                                    \
      _Pragma("unroll")                                                    \
      for (int bb = 0; bb < 4; ++bb) {                                     \
        float a = acc[bb][n];                                              \
        a = fmaf(CUR[bb][0].x, w0.x, a);                                   \
        a = fmaf(CUR[bb][0].y, w0.y, a);                                   \
        a = fmaf(CUR[bb][0].z, w0.z, a);                                   \
        a = fmaf(CUR[bb][0].w, w0.w, a);                                   \
        a = fmaf(CUR[bb][1].x, w1.x, a);                                   \
        a = fmaf(CUR[bb][1].y, w1.y, a);                                   \
        a = fmaf(CUR[bb][1].z, w1.z, a);                                   \
        a = fmaf(CUR[bb][1].w, w1.w, a);                                   \
        acc[bb][n] = a;                                                    \
      }                                                                    \
    }                                                                      \
  }

  for (int it = 0; it < 16; it += 2) {
    IT_BODY(it,     bufA, bufB)
    IT_BODY(it + 1, bufB, bufA)
  }
#undef IT_BODY

  // Combine the two w-halves: lane (tl, th) <-> (tl, th^1).
#pragma unroll
  for (int bb = 0; bb < 4; ++bb)
#pragma unroll
    for (int n = 0; n < kN; ++n)
      acc[bb][n] += __shfl_xor(acc[bb][n], 32);

  // Store: th=0 lanes write n 0..3, th=1 lanes write n 4..7 (both halves
  // hold the full sum). For fixed (b,n), 32 lanes store 32 consecutive t.
  if (tg < kNT) {
    const size_t s = (size_t)kFP * kNT;
    const int nb = th * 4;
#pragma unroll
    for (int bb = 0; bb < 4; ++bb) {
      const int b = wq * 4 + bb;
      float* ob =
          out + (((size_t)b * kO + g * kN + nb) * kFP + fi) * (size_t)kNT + tg;
#pragma unroll
      for (int j = 0; j < 4; ++j) ob[(size_t)j * s] = acc[bb][nb + j];
    }
  }
}

extern "C" void kernel_launch(void* const* d_in, const int* in_sizes, int n_in,
                              void* d_out, int out_size, void* d_ws, size_t ws_size,
                              hipStream_t stream) {
  const float* x  = (const float*)d_in[0];
  const float* wt = (const float*)d_in[1];
  float* out      = (float*)d_out;

  dim3 grid(kFP, kG, 2);   // 64 x 8 x 2 = 1024 blocks of 256 threads
  lc2d_kernel<<<grid, 256, 0, stream>>>(x, wt, out);
}

// Round 4
// 214.825 us; speedup vs baseline: 1.0771x; 1.0140x over previous
//
#include <hip/hip_runtime.h>

// LinearConv2D: y[b, o=g*8+n, fi, t] =
//   sum_{d<8, fr<2, w<16} x[b, g*8+d, 2*fi+fr, 4*t+w] * wt[g*8+n, d, 2*fi+fr, w]
// Shapes: x[16,64,128,256] f32, wt[64,8,128,16] f32, out[16,64,64,61] f32.
//
// R11: the ~50us plateau decoded. R4/R5/R7/R8/R10 (five weight paths, three
// occupancies) all land 47-57us because SIMD util ~= W*C/(C+E) with
// C = FMA-cy per weight batch, E ~= batch latency (~250cy SMEM drain /
// ~120cy LDS): all configs used ~128 batches/wave, and total VALU work per
// SIMD (32.8k cy) ~= 128 * 250 => util pinned at ~100% marginal => ~2x the
// 13.7us VALU floor. (SMEM is out-of-order: lgkmcnt(0) drains just-issued
// loads too, so issue-ahead can't beat E; LDS pays a 64x broadcast tax =
// 20us/CU port time on top.)
// Fix (changes the formula, not the path): batches/wave 128 -> 32 and W -> 8:
//  - weight batch = 4n x 16w = 64 floats = 64 SGPRs (8n = 128 doesn't fit
//    the ~102 budget). C = 128cy/batch. Weights ride the SCALAR operand of
//    v_fmac: zero VGPR cost, zero LDS, no broadcast amplification.
//  - wave = 1 b x 8 n x 64 t: acc[8] + single x row buffer => ~45 VGPR <= 64,
//    LDS 0 => 32 waves/CU (grid 64x8x4 blocks x 4 waves = 8192 waves).
//  - duty ~= 256/(320+128+300+128) ~= 29% x 8 waves ~= 235% coverage.
// Predicted: kernel ~22-30us, dur ~183-195 (fills ~158us are harness floor),
// VGPR<=64, LDS=0. Spill tripwire: WRITE_SIZE stays ~19.6MB.

namespace {
constexpr int kC  = 64;
constexpr int kF  = 128;
constexpr int kT  = 256;
constexpr int kD  = 8;
constexpr int kN  = 8;
constexpr int kW  = 16;
constexpr int kKS = 4;
constexpr int kNT = 61;   // (256-16)/4 + 1
constexpr int kO  = 64;
constexpr int kFP = 64;   // (128-2)/2 + 1
// Weight strides in float4 quads: n: 8*128*16/4 = 4096, d: 128*16/4 = 512,
// fr: 16/4 = 4.
constexpr int kQN = 4096;
constexpr int kQD = 512;
constexpr int kQF = 4;
}

__global__ __launch_bounds__(256, 8)
void lc2d_kernel(const float* __restrict__ x,
                 const float* __restrict__ wt,
                 float* __restrict__ out) {
  const int lane = threadIdx.x & 63;   // t
  const int wv   = threadIdx.x >> 6;   // wave id -> b
  const int fi   = blockIdx.x;         // 0..63 (scalar)
  const int g    = blockIdx.y;         // 0..7  (scalar)
  const int b    = blockIdx.z * 4 + wv;

  // Clamp inactive lanes (t >= 61) in-bounds.
  const int tc   = (lane < kNT) ? lane : (kNT - 1);
  const int tau0 = tc * kKS;           // max 240; +16 = 256 OK

  const float* xb =
      x + (((size_t)b * kC + g * kD) * kF + fi * 2) * kT + tau0;
  // Wave-uniform weight base (blockIdx only) -> scalar loads.
  const float4* wb =
      (const float4*)(wt + ((size_t)(g * kN) * kD * kF + (size_t)fi * 2) * kW);

  float acc[kN];
#pragma unroll
  for (int n = 0; n < kN; ++n) acc[n] = 0.f;

#pragma unroll 2
  for (int it = 0; it < 16; ++it) {
    const int d  = it >> 1;
    const int fr = it & 1;

    // x row for (d, fr): 4 coalesced float4 (this wave's b only).
    const float* xr = xb + ((size_t)d * kF + fr) * kT;
    const float4 c0 = ((const float4*)xr)[0];
    const float4 c1 = ((const float4*)xr)[1];
    const float4 c2 = ((const float4*)xr)[2];
    const float4 c3 = ((const float4*)xr)[3];

    const float4* wit = wb + d * kQD + fr * kQF;

    // Two batches of 4 n: 16 uniform float4 loads (s_load) per batch,
    // one drain each, then 4n x 16 FMAs with the weight as the SGPR operand.
#pragma unroll
    for (int nb = 0; nb < 2; ++nb) {
      float4 w[16];
#pragma unroll
      for (int j = 0; j < 16; ++j)
        w[j] = wit[(size_t)(nb * 4 + (j >> 2)) * kQN + (j & 3)];
#pragma unroll
      for (int nn = 0; nn < 4; ++nn) {
        const float4 w0 = w[nn * 4 + 0];
        const float4 w1 = w[nn * 4 + 1];
        const float4 w2 = w[nn * 4 + 2];
        const float4 w3 = w[nn * 4 + 3];
        float a = acc[nb * 4 + nn];
        a = fmaf(c0.x, w0.x, a);
        a = fmaf(c0.y, w0.y, a);
        a = fmaf(c0.z, w0.z, a);
        a = fmaf(c0.w, w0.w, a);
        a = fmaf(c1.x, w1.x, a);
        a = fmaf(c1.y, w1.y, a);
        a = fmaf(c1.z, w1.z, a);
        a = fmaf(c1.w, w1.w, a);
        a = fmaf(c2.x, w2.x, a);
        a = fmaf(c2.y, w2.y, a);
        a = fmaf(c2.z, w2.z, a);
        a = fmaf(c2.w, w2.w, a);
        a = fmaf(c3.x, w3.x, a);
        a = fmaf(c3.y, w3.y, a);
        a = fmaf(c3.z, w3.z, a);
        a = fmaf(c3.w, w3.w, a);
        acc[nb * 4 + nn] = a;
      }
    }
  }

  if (lane < kNT) {
    const size_t s = (size_t)kFP * kNT;
    float* ob =
        out + (((size_t)b * kO + g * kN) * kFP + fi) * (size_t)kNT + lane;
#pragma unroll
    for (int n = 0; n < kN; ++n) ob[(size_t)n * s] = acc[n];
  }
}

extern "C" void kernel_launch(void* const* d_in, const int* in_sizes, int n_in,
                              void* d_out, int out_size, void* d_ws, size_t ws_size,
                              hipStream_t stream) {
  const float* x  = (const float*)d_in[0];
  const float* wt = (const float*)d_in[1];
  float* out      = (float*)d_out;

  dim3 grid(kFP, 8, 4);   // 64 x 8 x 4 = 2048 blocks x 256 thr = 32 waves/CU
  lc2d_kernel<<<grid, 256, 0, stream>>>(x, wt, out);
}